// Round 3
// baseline (1656.124 us; speedup 1.0000x reference)
//
#include <hip/hip_runtime.h>
#include <cstdint>
#include <cstddef>

#define B_  2
#define H_  8
#define C_  2048
#define HW_ 64
#define HD_ 512   // H_*HW_

// ---------------- Projection + rotary phase ----------------
// grid: (C_/32, B_*H_), block 256
// Writes QrT/QiT transposed [bh][i][c] (for retention LDS staging),
// Kr/Ki/V natural [bh][c][i].
__global__ __launch_bounds__(256) void proj_kernel(
    const float* __restrict__ x, const float* __restrict__ WQ,
    const float* __restrict__ WK, const float* __restrict__ WV,
    const float* __restrict__ theta,
    float* __restrict__ QrT, float* __restrict__ QiT,
    float* __restrict__ Kr, float* __restrict__ Ki,
    float* __restrict__ V)
{
    __shared__ float smem[3 * 64 * 65 + 32 * 65];   // sW | sx ; reused for transpose
    float* sW = smem;               // [3][64][65]
    float* sx = smem + 3 * 64 * 65; // [32][65]
    int tid = threadIdx.x;
    int bh = blockIdx.y; int h = bh & 7;
    int c0 = blockIdx.x * 32;
    for (int t = tid; t < 64 * 64; t += 256) {
        int j = t & 63, i = t >> 6;
        int g = (h * 64 + i) * 64 + j;
        sW[0 * 64 * 65 + i * 65 + j] = WQ[g];
        sW[1 * 64 * 65 + i * 65 + j] = WK[g];
        sW[2 * 64 * 65 + i * 65 + j] = WV[g];
    }
    for (int t = tid; t < 32 * 64; t += 256) {
        int i = t & 63, c = t >> 6;
        sx[c * 65 + i] = x[((size_t)((bh >> 3) * C_ + c0 + c)) * HD_ + h * 64 + i];
    }
    __syncthreads();
    int j = tid & 63, cg = tid >> 6;   // cg 0..3, 8 c's each
    float aq[8] = {}, ak[8] = {}, av[8] = {};
    for (int i = 0; i < 64; ++i) {
        float w0 = sW[0 * 64 * 65 + i * 65 + j];
        float w1 = sW[1 * 64 * 65 + i * 65 + j];
        float w2 = sW[2 * 64 * 65 + i * 65 + j];
        #pragma unroll
        for (int cc = 0; cc < 8; ++cc) {
            float xv = sx[(cg * 8 + cc) * 65 + i];
            aq[cc] += xv * w0;
            ak[cc] += xv * w1;
            av[cc] += xv * w2;
        }
    }
    float th = theta[h * 64 + j];
    float qrv[8], qiv[8];
    #pragma unroll
    for (int cc = 0; cc < 8; ++cc) {
        int c = c0 + cg * 8 + cc;
        float sn, cs;
        sincosf((float)c * th, &sn, &cs);
        qrv[cc] = aq[cc] * cs; qiv[cc] = aq[cc] * sn;
        size_t o = ((size_t)bh * C_ + c) * HW_ + j;
        Kr[o] = ak[cc] * cs; Ki[o] = -ak[cc] * sn;
        V[o]  = av[cc];
    }
    __syncthreads();                    // everyone done reading sW/sx
    // LDS transpose of rotated Q: registers [j, 8 c] -> global [i=j][c]
    float* T0 = smem;                   // [64][33]
    float* T1 = smem + 64 * 33;
    #pragma unroll
    for (int cc = 0; cc < 8; ++cc) {
        T0[j * 33 + cg * 8 + cc] = qrv[cc];   // stride-33 rows: 2-way, free
        T1[j * 33 + cg * 8 + cc] = qiv[cc];
    }
    __syncthreads();
    int cc2 = tid & 31, jg = tid >> 5;  // 8 j-rows per thread, coalesced c stores
    size_t ibase = (size_t)bh * HW_ * C_;
    #pragma unroll
    for (int jj = 0; jj < 8; ++jj) {
        int jr = jg * 8 + jj;
        QrT[ibase + (size_t)jr * C_ + c0 + cc2] = T0[jr * 33 + cc2];
        QiT[ibase + (size_t)jr * C_ + c0 + cc2] = T1[jr * 33 + cc2];
    }
}

// ---------------- Retention core + per-row L2 normalize ----------------
// grid: (32 q-tiles of 64, B_*H_), block 256.
// 64x64 tiles; phase A 4c x 4d complex micro-tile (Q from LDS rows, K from
// global broadcast); S through 32KB LDS; phase B V from global broadcast.
// qt swizzled so co-resident block pairs (n, n+256) sum to 33 tiles.
__global__ __launch_bounds__(256) void retention_kernel(
    const float* __restrict__ QrT, const float* __restrict__ QiT,
    const float* __restrict__ Kr, const float* __restrict__ Ki,
    const float* __restrict__ V,
    float* __restrict__ OHr, float* __restrict__ OHi,
    const float* __restrict__ gamma, const float* __restrict__ qk_scale)
{
    __shared__ float smem[16384];       // 64 KB exactly
    float* sQr = smem;                  // [64 i][64 c]
    float* sQi = smem + 4096;
    float* sSr = smem + 8192;           // [64 d][64 c]
    float* sSi = smem + 12288;
    const int tid = threadIdx.x;
    const int bh = blockIdx.y, h = bh & 7, b = bh >> 3;
    const int qt = (bh < 8) ? (int)blockIdx.x : 31 - (int)blockIdx.x;
    const int qc0 = qt * 64;
    const size_t cbase = (size_t)bh * C_ * HW_;   // K, V: [c][i]
    const size_t ibase = (size_t)bh * HW_ * C_;   // QT:   [i][c]
    // stage Q tile [i][c] : coalesced global, contiguous LDS
    #pragma unroll
    for (int r = 0; r < 4; ++r) {
        int f = tid + r * 256;
        int i = f >> 4, c4 = (f & 15) * 4;
        *(float4*)&sQr[i * 64 + c4] = *(const float4*)&QrT[ibase + (size_t)i * C_ + qc0 + c4];
        *(float4*)&sQi[i * 64 + c4] = *(const float4*)&QiT[ibase + (size_t)i * C_ + qc0 + c4];
    }
    const float lg = log2f(gamma[h]);
    const float inv_scale = 1.0f / qk_scale[0];
    const int cq = tid & 63, ig = tid >> 6;           // phase-B map
    const int c0 = (tid & 15) * 4, d0 = (tid >> 4) * 4; // phase-A map
    float o_r[16], o_i[16];
    #pragma unroll
    for (int k = 0; k < 16; ++k) { o_r[k] = 0.0f; o_i[k] = 0.0f; }
    __syncthreads();
    for (int kt = 0; kt <= qt; ++kt) {
        const int kc0 = kt * 64;
        float rr[4][4] = {}, im[4][4] = {};
        const float* Kp  = Kr + cbase + (size_t)(kc0 + d0) * HW_;
        const float* Kip = Ki + cbase + (size_t)(kc0 + d0) * HW_;
        #pragma unroll 4
        for (int i0 = 0; i0 < 64; i0 += 4) {
            float krv[16], kiv[16];     // [dd*4+ii]
            #pragma unroll
            for (int dd = 0; dd < 4; ++dd) {
                *(float4*)&krv[dd * 4] = *(const float4*)&Kp[(size_t)dd * HW_ + i0];
                *(float4*)&kiv[dd * 4] = *(const float4*)&Kip[(size_t)dd * HW_ + i0];
            }
            #pragma unroll
            for (int ii = 0; ii < 4; ++ii) {
                float qr[4], qi_[4];
                *(float4*)&qr[0]  = *(const float4*)&sQr[(i0 + ii) * 64 + c0];
                *(float4*)&qi_[0] = *(const float4*)&sQi[(i0 + ii) * 64 + c0];
                #pragma unroll
                for (int dd = 0; dd < 4; ++dd) {
                    float kv = krv[dd * 4 + ii];
                    float kw = kiv[dd * 4 + ii];
                    #pragma unroll
                    for (int cc = 0; cc < 4; ++cc) {
                        rr[cc][dd] += qr[cc] * kv - qi_[cc] * kw;
                        im[cc][dd] += qr[cc] * kw + qi_[cc] * kv;
                    }
                }
            }
        }
        __syncthreads();   // prev phase-B reads of sS done; phase A done
        // decay weights: w = gamma^((qc0+c0+cc) - (kc0+d0+dd)) / scale, 0 if acausal
        float rowp[4];
        #pragma unroll
        for (int cc = 0; cc < 4; ++cc)
            rowp[cc] = exp2f(lg * (float)(qc0 + c0 + cc - kc0)) * inv_scale;
        #pragma unroll
        for (int dd = 0; dd < 4; ++dd) {
            float colp = exp2f(-lg * (float)(d0 + dd));
            float s0[4], s1[4];
            #pragma unroll
            for (int cc = 0; cc < 4; ++cc) {
                int delta = (qc0 + c0 + cc) - (kc0 + d0 + dd);
                float w = (delta >= 0) ? rowp[cc] * colp : 0.0f;
                s0[cc] = w * rr[cc][dd];
                s1[cc] = w * im[cc][dd];
            }
            *(float4*)&sSr[(d0 + dd) * 64 + c0] = *(float4*)&s0[0];
            *(float4*)&sSi[(d0 + dd) * 64 + c0] = *(float4*)&s1[0];
        }
        __syncthreads();
        // phase B: O[c][i] += S[c][d] * V[d][i]; V wave-uniform broadcast
        const float* Vp = V + cbase + (size_t)kc0 * HW_ + ig * 16;
        #pragma unroll 2
        for (int d = 0; d < 64; ++d) {
            float sr = sSr[d * 64 + cq], si = sSi[d * 64 + cq];
            float v[16];
            *(float4*)&v[0]  = *(const float4*)&Vp[(size_t)d * HW_];
            *(float4*)&v[4]  = *(const float4*)&Vp[(size_t)d * HW_ + 4];
            *(float4*)&v[8]  = *(const float4*)&Vp[(size_t)d * HW_ + 8];
            *(float4*)&v[12] = *(const float4*)&Vp[(size_t)d * HW_ + 12];
            #pragma unroll
            for (int k = 0; k < 16; ++k) {
                o_r[k] += sr * v[k];
                o_i[k] += si * v[k];
            }
        }
    }
    __syncthreads();   // last phase B done; reuse sSr for norm reduction
    float ss = 0.0f;
    #pragma unroll
    for (int k = 0; k < 16; ++k) ss += o_r[k] * o_r[k] + o_i[k] * o_i[k];
    sSr[ig * 64 + cq] = ss;
    __syncthreads();
    float tot = sSr[cq] + sSr[64 + cq] + sSr[128 + cq] + sSr[192 + cq];
    float rn = 1.0f / sqrtf(tot);
    size_t o = ((size_t)(b * C_ + qc0 + cq) * H_ + h) * HW_ + ig * 16;
    float so[16];
    #pragma unroll
    for (int k = 0; k < 16; ++k) so[k] = o_r[k] * rn;
    #pragma unroll
    for (int q4 = 0; q4 < 4; ++q4) *(float4*)&OHr[o + q4 * 4] = *(float4*)&so[q4 * 4];
    #pragma unroll
    for (int k = 0; k < 16; ++k) so[k] = o_i[k] * rn;
    #pragma unroll
    for (int q4 = 0; q4 < 4; ++q4) *(float4*)&OHi[o + q4 * 4] = *(float4*)&so[q4 * 4];
}

// ---------------- fp32 GEMM: C[M,N] = A[M,K]*B[K,N] ----------------
// BM=BN=128, BK=8, 256 threads, 8x8 micro-tile.
// mode 0: plain store; mode 1: complex interleave (rows [0,M/2) = re, rest = im);
// mode 2: store real plane only.
// NOTE: epilogue loops MUST be fully unrolled — dynamic acc[im][in] indexing
// in a non-unrolled loop demotes the whole accumulator to scratch (R1: 52
// VGPRs, 2.2 GB scratch writes, 1950 us).
__global__ __launch_bounds__(256) void gemm_kernel(
    const float* __restrict__ A, const float* __restrict__ Bm,
    float* __restrict__ Cout, int M, int N, int K, int mode)
{
    __shared__ float sA[8][132];   // 132 floats = 528B rows, 16B-aligned
    __shared__ float sB[8][132];
    int tid = threadIdx.x;
    int bm = blockIdx.x * 128, bn = blockIdx.y * 128;
    int tx = tid & 15, ty = tid >> 4;
    int m0 = ty * 8, n0 = tx * 8;
    float acc[8][8] = {};
    for (int k0 = 0; k0 < K; k0 += 8) {
        #pragma unroll
        for (int t = tid; t < 1024; t += 256) {
            int kk = t & 7, m = t >> 3;
            sA[kk][m] = A[(size_t)(bm + m) * K + k0 + kk];
        }
        #pragma unroll
        for (int t = tid; t < 1024; t += 256) {
            int n = t & 127, kk = t >> 7;
            sB[kk][n] = Bm[(size_t)(k0 + kk) * N + bn + n];
        }
        __syncthreads();
        #pragma unroll
        for (int kk = 0; kk < 8; ++kk) {
            float a_[8], b_[8];
            *(float4*)&a_[0] = *(const float4*)&sA[kk][m0];
            *(float4*)&a_[4] = *(const float4*)&sA[kk][m0 + 4];
            *(float4*)&b_[0] = *(const float4*)&sB[kk][n0];
            *(float4*)&b_[4] = *(const float4*)&sB[kk][n0 + 4];
            #pragma unroll
            for (int im = 0; im < 8; ++im)
                #pragma unroll
                for (int in = 0; in < 8; ++in)
                    acc[im][in] += a_[im] * b_[in];
        }
        __syncthreads();
    }
    int half = M >> 1;
    #pragma unroll
    for (int im = 0; im < 8; ++im) {
        int m = bm + m0 + im;
        #pragma unroll
        for (int in = 0; in < 8; ++in) {
            int n = bn + n0 + in;
            float vv = acc[im][in];
            if (mode == 0) {
                Cout[(size_t)m * N + n] = vv;
            } else if (mode == 1) {
                if (m < half) Cout[2 * ((size_t)m * N + n)] = vv;
                else          Cout[2 * ((size_t)(m - half) * N + n) + 1] = vv;
            } else {
                if (m < half) Cout[(size_t)m * N + n] = vv;
            }
        }
    }
}

// ---------------- complex gate: oh' = oh*g / (1 + exp(-2g)), g complex ----------------
__global__ __launch_bounds__(256) void gate_kernel(
    const float* __restrict__ OHr, const float* __restrict__ OHi,
    const float* __restrict__ G,
    float* __restrict__ O2r, float* __restrict__ O2i, int n)
{
    int idx = blockIdx.x * 256 + threadIdx.x;
    if (idx >= n) return;
    float gr = G[idx], gi = G[idx + n];
    float hr = OHr[idx], hi = OHi[idx];
    float e = expf(-2.0f * gr);
    float sn, cs;
    sincosf(2.0f * gi, &sn, &cs);
    float dr = 1.0f + e * cs;     // 1 + exp(-2g) = (1 + e*cos(2gi)) - i*e*sin(2gi)
    float di = -e * sn;
    float nr = hr * gr - hi * gi; // oh * g
    float ni = hr * gi + hi * gr;
    float inv = 1.0f / (dr * dr + di * di);
    O2r[idx] = (nr * dr + ni * di) * inv;
    O2i[idx] = (ni * dr - nr * di) * inv;
}

extern "C" void kernel_launch(void* const* d_in, const int* in_sizes, int n_in,
                              void* d_out, int out_size, void* d_ws, size_t ws_size,
                              hipStream_t stream)
{
    const float* x     = (const float*)d_in[0];
    const float* WQ    = (const float*)d_in[1];
    const float* WK    = (const float*)d_in[2];
    const float* WV    = (const float*)d_in[3];
    const float* theta = (const float*)d_in[4];
    const float* gamma = (const float*)d_in[5];
    // d_in[6] target_norm: dead in reference
    const float* qk    = (const float*)d_in[7];
    const float* WO    = (const float*)d_in[8];
    const float* WG    = (const float*)d_in[9];
    float* out = (float*)d_out;
    float* w = (float*)d_ws;

    const size_t N1 = (size_t)B_ * H_ * C_ * HW_;  // 2,097,152 (also = B*C*512)
    float *QrT = w,           *QiT = w + N1,     *Kr = w + 2 * N1,
          *Ki = w + 3 * N1,   *V  = w + 4 * N1;
    float *OHr = w + 5 * N1,  *OHi = w + 6 * N1;  // contiguous -> stacked GEMM A
    float *G   = w + 7 * N1;                      // 2*N1 (re plane, im plane)
    float *O2r = w + 9 * N1,  *O2i = w + 10 * N1; // contiguous pair

    proj_kernel<<<dim3(C_ / 32, B_ * H_), 256, 0, stream>>>(
        x, WQ, WK, WV, theta, QrT, QiT, Kr, Ki, V);
    retention_kernel<<<dim3(C_ / 64, B_ * H_), 256, 0, stream>>>(
        QrT, QiT, Kr, Ki, V, OHr, OHi, gamma, qk);

    const int M = 2 * B_ * C_;  // 8192 rows: [re; im] planes
    gemm_kernel<<<dim3(M / 128, HD_ / 128), 256, 0, stream>>>(
        OHr, WG, G, M, HD_, HD_, 0);

    int n1i = (int)N1;
    gate_kernel<<<dim3((n1i + 255) / 256), 256, 0, stream>>>(
        OHr, OHi, G, O2r, O2i, n1i);

    int outmode = (out_size >= (int)(2 * N1)) ? 1 : 2;  // complex interleave vs real-only
    gemm_kernel<<<dim3(M / 128, HD_ / 128), 256, 0, stream>>>(
        O2r, WO, out, M, HD_, HD_, outmode);
}

// Round 4
// 685.055 us; speedup vs baseline: 2.4175x; 2.4175x over previous
//
#include <hip/hip_runtime.h>
#include <cstdint>
#include <cstddef>

#define B_  2
#define H_  8
#define C_  2048
#define HW_ 64
#define HD_ 512   // H_*HW_

typedef __attribute__((ext_vector_type(8))) short short8;
typedef __attribute__((ext_vector_type(4))) short short4v;
typedef __attribute__((ext_vector_type(4))) float f32x4;
typedef __attribute__((ext_vector_type(4))) int   int4v;
typedef unsigned short us;

static __device__ inline us f2bf(float f) {
    unsigned u = __builtin_bit_cast(unsigned, f);
    u = u + 0x7FFFu + ((u >> 16) & 1u);          // RNE
    return (us)(u >> 16);
}
static __device__ inline float bf2f(us s) {
    unsigned u = ((unsigned)s) << 16;
    return __builtin_bit_cast(float, u);
}
static __device__ inline f32x4 mfma16(short8 a, short8 b, f32x4 c) {
    return __builtin_amdgcn_mfma_f32_16x16x32_bf16(a, b, c, 0, 0, 0);
}
static __device__ inline short8 negbf(short8 v) {   // flip bf16 sign bits
    int4v u = __builtin_bit_cast(int4v, v);
    u ^= (int)0x80008000;
    return __builtin_bit_cast(short8, u);
}
// b64-pair LDS fragment load (rows padded to 68 shorts -> only 8B-aligned)
static __device__ inline short8 lds_frag(const us* p) {
    short4v a = *(const short4v*)p;
    short4v b = *(const short4v*)(p + 4);
    return __builtin_shufflevector(a, b, 0, 1, 2, 3, 4, 5, 6, 7);
}

// ---------------- Projection + rotary phase ----------------
// grid: (C_/32, B_*H_), block 256.
// Emits bf16 split (hi/lo) planes:
//   Qcat [bh][c][128] = [Qr | Qi]
//   K1   [bh][c][128] = [Kr | -Ki]   (K2=[Ki|Kr] derived in retention)
//   VT   [bh][i][c]   = V transposed
__global__ __launch_bounds__(256) void proj_kernel(
    const float* __restrict__ x, const float* __restrict__ WQ,
    const float* __restrict__ WK, const float* __restrict__ WV,
    const float* __restrict__ theta,
    us* __restrict__ Qch, us* __restrict__ Qcl,
    us* __restrict__ K1h, us* __restrict__ K1l,
    us* __restrict__ VTh, us* __restrict__ VTl)
{
    __shared__ float smem[3 * 64 * 65 + 32 * 65];
    float* sW = smem;               // [3][64][65]
    float* sx = smem + 3 * 64 * 65; // [32][65]
    int tid = threadIdx.x;
    int bh = blockIdx.y; int h = bh & 7;
    int c0 = blockIdx.x * 32;
    for (int t = tid; t < 64 * 64; t += 256) {
        int j = t & 63, i = t >> 6;
        int g = (h * 64 + i) * 64 + j;
        sW[0 * 64 * 65 + i * 65 + j] = WQ[g];
        sW[1 * 64 * 65 + i * 65 + j] = WK[g];
        sW[2 * 64 * 65 + i * 65 + j] = WV[g];
    }
    for (int t = tid; t < 32 * 64; t += 256) {
        int i = t & 63, c = t >> 6;
        sx[c * 65 + i] = x[((size_t)((bh >> 3) * C_ + c0 + c)) * HD_ + h * 64 + i];
    }
    __syncthreads();
    int j = tid & 63, cg = tid >> 6;   // cg 0..3, 8 c's each
    float aq[8] = {}, ak[8] = {}, av[8] = {};
    for (int i = 0; i < 64; ++i) {
        float w0 = sW[0 * 64 * 65 + i * 65 + j];
        float w1 = sW[1 * 64 * 65 + i * 65 + j];
        float w2 = sW[2 * 64 * 65 + i * 65 + j];
        #pragma unroll
        for (int cc = 0; cc < 8; ++cc) {
            float xv = sx[(cg * 8 + cc) * 65 + i];
            aq[cc] += xv * w0;
            ak[cc] += xv * w1;
            av[cc] += xv * w2;
        }
    }
    float th = theta[h * 64 + j];
    #pragma unroll
    for (int cc = 0; cc < 8; ++cc) {
        int c = c0 + cg * 8 + cc;
        float sn, cs;
        sincosf((float)c * th, &sn, &cs);
        float qr = aq[cc] * cs, qi = aq[cc] * sn;
        float kr = ak[cc] * cs, nki = ak[cc] * sn;   // nki = -Ki (K uses conj phase)
        size_t rq = ((size_t)bh * C_ + c) * 128;
        us h0;
        h0 = f2bf(qr);  Qch[rq + j]      = h0; Qcl[rq + j]      = f2bf(qr  - bf2f(h0));
        h0 = f2bf(qi);  Qch[rq + 64 + j] = h0; Qcl[rq + 64 + j] = f2bf(qi  - bf2f(h0));
        h0 = f2bf(kr);  K1h[rq + j]      = h0; K1l[rq + j]      = f2bf(kr  - bf2f(h0));
        h0 = f2bf(nki); K1h[rq + 64 + j] = h0; K1l[rq + 64 + j] = f2bf(nki - bf2f(h0));
    }
    __syncthreads();                    // done reading sW/sx
    // LDS transpose of V: registers [j, 8 c] -> global VT[i=j][c]
    float* T0 = smem;                   // [64][33]
    #pragma unroll
    for (int cc = 0; cc < 8; ++cc)
        T0[j * 33 + cg * 8 + cc] = av[cc];
    __syncthreads();
    int cc2 = tid & 31, jg = tid >> 5;  // 8 j-rows per thread, coalesced c stores
    #pragma unroll
    for (int jj = 0; jj < 8; ++jj) {
        int jr = jg * 8 + jj;
        float v = T0[jr * 33 + cc2];
        us hh = f2bf(v);
        size_t o = ((size_t)bh * 64 + jr) * C_ + c0 + cc2;
        VTh[o] = hh;
        VTl[o] = f2bf(v - bf2f(hh));
    }
}

// ---------------- MFMA Retention + per-row L2 normalize ----------------
// grid: (32, 16) -> (qt = 31-bx for big-first dispatch, bh). Block 256 = 4 waves.
// Wave w owns queries [qc0 + 16w, +16). Split-bf16 (hi+lo, 3 MFMA) everywhere.
//   Sr = Qcat.K1^T, Si = Qcat.K2^T with K2 frags derived from K1 (swap+neg).
//   Phase B: O += S.V via LDS round-trip of S (C/D-layout -> A-layout).
// LDS: 4 S planes + 2 V^T planes, rows padded to 68 shorts (write 2-way=free).
__global__ __launch_bounds__(256) void retention_kernel(
    const us* __restrict__ Qch, const us* __restrict__ Qcl,
    const us* __restrict__ K1h, const us* __restrict__ K1l,
    const us* __restrict__ VTh, const us* __restrict__ VTl,
    float* __restrict__ OHr, float* __restrict__ OHi,
    const float* __restrict__ gamma, const float* __restrict__ qk_scale)
{
    constexpr int SP = 68;             // padded row stride (shorts)
    constexpr int PL = 64 * SP;        // plane size
    __shared__ us smem[6 * PL];        // 52,224 B -> 3 blocks/CU
    us* sSrh = smem;
    us* sSrl = smem + PL;
    us* sSih = smem + 2 * PL;
    us* sSil = smem + 3 * PL;
    us* sVh  = smem + 4 * PL;
    us* sVl  = smem + 5 * PL;

    const int tid = threadIdx.x;
    const int w = tid >> 6, lane = tid & 63;
    const int ln = lane & 15, quad = lane >> 4;
    const int bh = blockIdx.y, h = bh & 7, b = bh >> 3;
    const int qt = 31 - (int)blockIdx.x;       // big blocks dispatch first
    const int qc0 = qt * 64;
    const float lg = log2f(gamma[h]);
    const float inv_scale = 1.0f / qk_scale[0];

    // persistent Q A-frags: A[m][k], m = qc0+16w+ln, k = ck*32 + quad*8 + j
    short8 Qh[4], Ql[4];
    {
        size_t qrow = ((size_t)bh * C_ + qc0 + w * 16 + ln) * 128;
        #pragma unroll
        for (int ck = 0; ck < 4; ++ck) {
            size_t off = qrow + ck * 32 + quad * 8;
            Qh[ck] = *(const short8*)(Qch + off);
            Ql[ck] = *(const short8*)(Qcl + off);
        }
    }
    f32x4 zz = {0.0f, 0.0f, 0.0f, 0.0f};
    f32x4 Or[4], Oi[4];
    #pragma unroll
    for (int it = 0; it < 4; ++it) { Or[it] = zz; Oi[it] = zz; }

    const size_t vtb = (size_t)bh * 64 * C_;
    for (int kt = 0; kt <= qt; ++kt) {
        const int kc0 = kt * 64;
        __syncthreads();   // prev phase-B reads of sV done
        // stage V^T tile: sV[i][c-local], 16 shorts/thread/plane
        {
            int i = tid >> 2, seg = (tid & 3) * 16;
            size_t g = vtb + (size_t)i * C_ + kc0 + seg;
            short8 a = *(const short8*)(VTh + g);
            short8 bq = *(const short8*)(VTh + g + 8);
            *(short4v*)&sVh[i * SP + seg]      = __builtin_shufflevector(a, a, 0, 1, 2, 3);
            *(short4v*)&sVh[i * SP + seg + 4]  = __builtin_shufflevector(a, a, 4, 5, 6, 7);
            *(short4v*)&sVh[i * SP + seg + 8]  = __builtin_shufflevector(bq, bq, 0, 1, 2, 3);
            *(short4v*)&sVh[i * SP + seg + 12] = __builtin_shufflevector(bq, bq, 4, 5, 6, 7);
            a  = *(const short8*)(VTl + g);
            bq = *(const short8*)(VTl + g + 8);
            *(short4v*)&sVl[i * SP + seg]      = __builtin_shufflevector(a, a, 0, 1, 2, 3);
            *(short4v*)&sVl[i * SP + seg + 4]  = __builtin_shufflevector(a, a, 4, 5, 6, 7);
            *(short4v*)&sVl[i * SP + seg + 8]  = __builtin_shufflevector(bq, bq, 0, 1, 2, 3);
            *(short4v*)&sVl[i * SP + seg + 12] = __builtin_shufflevector(bq, bq, 4, 5, 6, 7);
        }
        // phase A: 16x16 S-tile pairs, keys kc0+16nt..+15 (B-frags from global)
        #pragma unroll
        for (int nt = 0; nt < 4; ++nt) {
            short8 Kh[4], Kl[4];
            size_t krow = ((size_t)bh * C_ + kc0 + nt * 16 + ln) * 128;
            #pragma unroll
            for (int ck = 0; ck < 4; ++ck) {
                size_t off = krow + ck * 32 + quad * 8;
                Kh[ck] = *(const short8*)(K1h + off);
                Kl[ck] = *(const short8*)(K1l + off);
            }
            f32x4 sr = zz, si = zz;
            #pragma unroll
            for (int ck = 0; ck < 4; ++ck) {
                sr = mfma16(Qh[ck], Kh[ck], sr);
                sr = mfma16(Qh[ck], Kl[ck], sr);
                sr = mfma16(Ql[ck], Kh[ck], sr);
            }
            short8 nKh2 = negbf(Kh[2]), nKh3 = negbf(Kh[3]);
            short8 nKl2 = negbf(Kl[2]), nKl3 = negbf(Kl[3]);
            si = mfma16(Qh[0], nKh2, si); si = mfma16(Qh[0], nKl2, si); si = mfma16(Ql[0], nKh2, si);
            si = mfma16(Qh[1], nKh3, si); si = mfma16(Qh[1], nKl3, si); si = mfma16(Ql[1], nKh3, si);
            si = mfma16(Qh[2], Kh[0], si); si = mfma16(Qh[2], Kl[0], si); si = mfma16(Ql[2], Kh[0], si);
            si = mfma16(Qh[3], Kh[1], si); si = mfma16(Qh[3], Kl[1], si); si = mfma16(Ql[3], Kh[1], si);
            // decay + causal mask on C-regs (D[m][n]: m=quad*4+r, n=ln), split->LDS
            int kglob = kc0 + nt * 16 + ln;
            int qbase = qc0 + w * 16 + quad * 4;
            #pragma unroll
            for (int r = 0; r < 4; ++r) {
                int delta = qbase + r - kglob;
                float wgt = (delta >= 0) ? exp2f(lg * (float)delta) * inv_scale : 0.0f;
                float a = sr[r] * wgt, c = si[r] * wgt;
                int ad = (w * 16 + quad * 4 + r) * SP + nt * 16 + ln;
                us h0 = f2bf(a); sSrh[ad] = h0; sSrl[ad] = f2bf(a - bf2f(h0));
                us h1 = f2bf(c); sSih[ad] = h1; sSil[ad] = f2bf(c - bf2f(h1));
            }
        }
        __syncthreads();   // sV staging + (wave-private) S writes complete
        // phase B: O[q][i] += S[q][kc] * V[kc][i]
        short8 SrH[2], SrL[2], SiH[2], SiL[2];
        int sb = (w * 16 + ln) * SP;
        #pragma unroll
        for (int ck2 = 0; ck2 < 2; ++ck2) {
            int off = sb + ck2 * 32 + quad * 8;
            SrH[ck2] = lds_frag(&sSrh[off]);
            SrL[ck2] = lds_frag(&sSrl[off]);
            SiH[ck2] = lds_frag(&sSih[off]);
            SiL[ck2] = lds_frag(&sSil[off]);
        }
        #pragma unroll
        for (int it = 0; it < 4; ++it) {
            int vb = (it * 16 + ln) * SP;
            #pragma unroll
            for (int ck2 = 0; ck2 < 2; ++ck2) {
                short8 Vh = lds_frag(&sVh[vb + ck2 * 32 + quad * 8]);
                short8 Vl = lds_frag(&sVl[vb + ck2 * 32 + quad * 8]);
                Or[it] = mfma16(SrH[ck2], Vh, Or[it]);
                Or[it] = mfma16(SrH[ck2], Vl, Or[it]);
                Or[it] = mfma16(SrL[ck2], Vh, Or[it]);
                Oi[it] = mfma16(SiH[ck2], Vh, Oi[it]);
                Oi[it] = mfma16(SiH[ck2], Vl, Oi[it]);
                Oi[it] = mfma16(SiL[ck2], Vh, Oi[it]);
            }
        }
    }
    // per-query L2 norm: lane holds (q = qbase+r, i = it*16+ln); reduce over ln
    float rn[4];
    #pragma unroll
    for (int r = 0; r < 4; ++r) {
        float ss = 0.0f;
        #pragma unroll
        for (int it = 0; it < 4; ++it)
            ss += Or[it][r] * Or[it][r] + Oi[it][r] * Oi[it][r];
        ss += __shfl_xor(ss, 1);
        ss += __shfl_xor(ss, 2);
        ss += __shfl_xor(ss, 4);
        ss += __shfl_xor(ss, 8);
        rn[r] = rsqrtf(ss);
    }
    #pragma unroll
    for (int it = 0; it < 4; ++it) {
        #pragma unroll
        for (int r = 0; r < 4; ++r) {
            int q = qc0 + w * 16 + quad * 4 + r;
            int i = it * 16 + ln;
            size_t o = (((size_t)(b * C_ + q)) * H_ + h) * HW_ + i;
            OHr[o] = Or[it][r] * rn[r];
            OHi[o] = Oi[it][r] * rn[r];
        }
    }
}

// ---------------- fp32 GEMM: C[M,N] = A[M,K]*B[K,N] ----------------
// BM=BN=128, BK=8, 256 threads, 8x8 micro-tile.
// mode 0: plain store; mode 1: complex interleave (rows [0,M/2) = re, rest = im);
// mode 2: store real plane only.
// NOTE: epilogue loops MUST be fully unrolled — dynamic acc[im][in] indexing
// in a non-unrolled loop demotes the whole accumulator to scratch (R1: 52
// VGPRs, 2.2 GB scratch writes, 1950 us).
__global__ __launch_bounds__(256) void gemm_kernel(
    const float* __restrict__ A, const float* __restrict__ Bm,
    float* __restrict__ Cout, int M, int N, int K, int mode)
{
    __shared__ float sA[8][132];
    __shared__ float sB[8][132];
    int tid = threadIdx.x;
    int bm = blockIdx.x * 128, bn = blockIdx.y * 128;
    int tx = tid & 15, ty = tid >> 4;
    int m0 = ty * 8, n0 = tx * 8;
    float acc[8][8] = {};
    for (int k0 = 0; k0 < K; k0 += 8) {
        #pragma unroll
        for (int t = tid; t < 1024; t += 256) {
            int kk = t & 7, m = t >> 3;
            sA[kk][m] = A[(size_t)(bm + m) * K + k0 + kk];
        }
        #pragma unroll
        for (int t = tid; t < 1024; t += 256) {
            int n = t & 127, kk = t >> 7;
            sB[kk][n] = Bm[(size_t)(k0 + kk) * N + bn + n];
        }
        __syncthreads();
        #pragma unroll
        for (int kk = 0; kk < 8; ++kk) {
            float a_[8], b_[8];
            *(float4*)&a_[0] = *(const float4*)&sA[kk][m0];
            *(float4*)&a_[4] = *(const float4*)&sA[kk][m0 + 4];
            *(float4*)&b_[0] = *(const float4*)&sB[kk][n0];
            *(float4*)&b_[4] = *(const float4*)&sB[kk][n0 + 4];
            #pragma unroll
            for (int im = 0; im < 8; ++im)
                #pragma unroll
                for (int in = 0; in < 8; ++in)
                    acc[im][in] += a_[im] * b_[in];
        }
        __syncthreads();
    }
    int half = M >> 1;
    #pragma unroll
    for (int im = 0; im < 8; ++im) {
        int m = bm + m0 + im;
        #pragma unroll
        for (int in = 0; in < 8; ++in) {
            int n = bn + n0 + in;
            float vv = acc[im][in];
            if (mode == 0) {
                Cout[(size_t)m * N + n] = vv;
            } else if (mode == 1) {
                if (m < half) Cout[2 * ((size_t)m * N + n)] = vv;
                else          Cout[2 * ((size_t)(m - half) * N + n) + 1] = vv;
            } else {
                if (m < half) Cout[(size_t)m * N + n] = vv;
            }
        }
    }
}

// ---------------- complex gate: oh' = oh*g / (1 + exp(-2g)), g complex ----------------
__global__ __launch_bounds__(256) void gate_kernel(
    const float* __restrict__ OHr, const float* __restrict__ OHi,
    const float* __restrict__ G,
    float* __restrict__ O2r, float* __restrict__ O2i, int n)
{
    int idx = blockIdx.x * 256 + threadIdx.x;
    if (idx >= n) return;
    float gr = G[idx], gi = G[idx + n];
    float hr = OHr[idx], hi = OHi[idx];
    float e = expf(-2.0f * gr);
    float sn, cs;
    sincosf(2.0f * gi, &sn, &cs);
    float dr = 1.0f + e * cs;
    float di = -e * sn;
    float nr = hr * gr - hi * gi;
    float ni = hr * gi + hi * gr;
    float inv = 1.0f / (dr * dr + di * di);
    O2r[idx] = (nr * dr + ni * di) * inv;
    O2i[idx] = (ni * dr - nr * di) * inv;
}

extern "C" void kernel_launch(void* const* d_in, const int* in_sizes, int n_in,
                              void* d_out, int out_size, void* d_ws, size_t ws_size,
                              hipStream_t stream)
{
    const float* x     = (const float*)d_in[0];
    const float* WQ    = (const float*)d_in[1];
    const float* WK    = (const float*)d_in[2];
    const float* WV    = (const float*)d_in[3];
    const float* theta = (const float*)d_in[4];
    const float* gamma = (const float*)d_in[5];
    // d_in[6] target_norm: dead in reference
    const float* qk    = (const float*)d_in[7];
    const float* WO    = (const float*)d_in[8];
    const float* WG    = (const float*)d_in[9];
    float* out = (float*)d_out;

    const size_t N1 = (size_t)B_ * H_ * C_ * HW_;       // 2,097,152
    const size_t SQ = (size_t)B_ * H_ * C_ * 128;       // shorts per Qcat/K1 plane
    const size_t SV = (size_t)B_ * H_ * HW_ * C_;       // shorts per VT plane
    us* usw = (us*)d_ws;
    us *Qch = usw,            *Qcl = usw + SQ,
       *K1h = usw + 2 * SQ,   *K1l = usw + 3 * SQ,
       *VTh = usw + 4 * SQ,   *VTl = usw + 4 * SQ + SV; // shorts end at 5*N1 floats
    float* fw = (float*)d_ws;
    float *OHr = fw + 5 * N1, *OHi = fw + 6 * N1;
    float *G   = fw + 7 * N1;                           // 2*N1 (re, im planes)
    float *O2r = fw + 9 * N1, *O2i = fw + 10 * N1;

    proj_kernel<<<dim3(C_ / 32, B_ * H_), 256, 0, stream>>>(
        x, WQ, WK, WV, theta, Qch, Qcl, K1h, K1l, VTh, VTl);
    retention_kernel<<<dim3(32, B_ * H_), 256, 0, stream>>>(
        Qch, Qcl, K1h, K1l, VTh, VTl, OHr, OHi, gamma, qk);

    const int M = 2 * B_ * C_;  // 8192 rows: [re; im] planes
    gemm_kernel<<<dim3(M / 128, HD_ / 128), 256, 0, stream>>>(
        OHr, WG, G, M, HD_, HD_, 0);

    int n1i = (int)N1;
    gate_kernel<<<dim3((n1i + 255) / 256), 256, 0, stream>>>(
        OHr, OHi, G, O2r, O2i, n1i);

    int outmode = (out_size >= (int)(2 * N1)) ? 1 : 2;
    gemm_kernel<<<dim3(M / 128, HD_ / 128), 256, 0, stream>>>(
        O2r, WO, out, M, HD_, HD_, outmode);
}

// Round 5
// 569.226 us; speedup vs baseline: 2.9094x; 1.2035x over previous
//
#include <hip/hip_runtime.h>
#include <cstdint>
#include <cstddef>

#define B_  2
#define H_  8
#define C_  2048
#define HW_ 64
#define HD_ 512   // H_*HW_

typedef __attribute__((ext_vector_type(8))) short short8;
typedef __attribute__((ext_vector_type(4))) short short4v;
typedef __attribute__((ext_vector_type(4))) float f32x4;
typedef __attribute__((ext_vector_type(4))) int   int4v;
typedef unsigned short us;

static __device__ inline us f2bf(float f) {           // RNE (used in proj)
    unsigned u = __builtin_bit_cast(unsigned, f);
    u = u + 0x7FFFu + ((u >> 16) & 1u);
    return (us)(u >> 16);
}
static __device__ inline us f2bf_t(float f) {         // truncate (hot path)
    return (us)(__builtin_bit_cast(unsigned, f) >> 16);
}
static __device__ inline float bf2f(us s) {
    unsigned u = ((unsigned)s) << 16;
    return __builtin_bit_cast(float, u);
}
static __device__ inline f32x4 mfma16(short8 a, short8 b, f32x4 c) {
    return __builtin_amdgcn_mfma_f32_16x16x32_bf16(a, b, c, 0, 0, 0);
}
static __device__ inline short8 negbf(short8 v) {
    int4v u = __builtin_bit_cast(int4v, v);
    u ^= (int)0x80008000;
    return __builtin_bit_cast(short8, u);
}
// b64-pair LDS fragment load (rows padded to 68 shorts -> only 8B-aligned)
static __device__ inline short8 lds_frag(const us* p) {
    short4v a = *(const short4v*)p;
    short4v b = *(const short4v*)(p + 4);
    return __builtin_shufflevector(a, b, 0, 1, 2, 3, 4, 5, 6, 7);
}

// ---------------- Projection + rotary phase ----------------
// grid: (C_/32, B_*H_), block 256.
// Emits bf16 split (hi/lo) planes:
//   Qcat [bh][c][128] = [Qr | Qi]
//   K1   [bh][c][128] = [Kr | -Ki]   (K2=[Ki|Kr] derived in retention)
//   VT   [bh][i][c]   = V transposed
__global__ __launch_bounds__(256) void proj_kernel(
    const float* __restrict__ x, const float* __restrict__ WQ,
    const float* __restrict__ WK, const float* __restrict__ WV,
    const float* __restrict__ theta,
    us* __restrict__ Qch, us* __restrict__ Qcl,
    us* __restrict__ K1h, us* __restrict__ K1l,
    us* __restrict__ VTh, us* __restrict__ VTl)
{
    __shared__ float smem[3 * 64 * 65 + 32 * 65];
    float* sW = smem;               // [3][64][65]
    float* sx = smem + 3 * 64 * 65; // [32][65]
    int tid = threadIdx.x;
    int bh = blockIdx.y; int h = bh & 7;
    int c0 = blockIdx.x * 32;
    for (int t = tid; t < 64 * 64; t += 256) {
        int j = t & 63, i = t >> 6;
        int g = (h * 64 + i) * 64 + j;
        sW[0 * 64 * 65 + i * 65 + j] = WQ[g];
        sW[1 * 64 * 65 + i * 65 + j] = WK[g];
        sW[2 * 64 * 65 + i * 65 + j] = WV[g];
    }
    for (int t = tid; t < 32 * 64; t += 256) {
        int i = t & 63, c = t >> 6;
        sx[c * 65 + i] = x[((size_t)((bh >> 3) * C_ + c0 + c)) * HD_ + h * 64 + i];
    }
    __syncthreads();
    int j = tid & 63, cg = tid >> 6;   // cg 0..3, 8 c's each
    float aq[8] = {}, ak[8] = {}, av[8] = {};
    for (int i = 0; i < 64; ++i) {
        float w0 = sW[0 * 64 * 65 + i * 65 + j];
        float w1 = sW[1 * 64 * 65 + i * 65 + j];
        float w2 = sW[2 * 64 * 65 + i * 65 + j];
        #pragma unroll
        for (int cc = 0; cc < 8; ++cc) {
            float xv = sx[(cg * 8 + cc) * 65 + i];
            aq[cc] += xv * w0;
            ak[cc] += xv * w1;
            av[cc] += xv * w2;
        }
    }
    float th = theta[h * 64 + j];
    #pragma unroll
    for (int cc = 0; cc < 8; ++cc) {
        int c = c0 + cg * 8 + cc;
        float sn, cs;
        sincosf((float)c * th, &sn, &cs);
        float qr = aq[cc] * cs, qi = aq[cc] * sn;
        float kr = ak[cc] * cs, nki = ak[cc] * sn;   // nki = -Ki (K uses conj phase)
        size_t rq = ((size_t)bh * C_ + c) * 128;
        us h0;
        h0 = f2bf(qr);  Qch[rq + j]      = h0; Qcl[rq + j]      = f2bf(qr  - bf2f(h0));
        h0 = f2bf(qi);  Qch[rq + 64 + j] = h0; Qcl[rq + 64 + j] = f2bf(qi  - bf2f(h0));
        h0 = f2bf(kr);  K1h[rq + j]      = h0; K1l[rq + j]      = f2bf(kr  - bf2f(h0));
        h0 = f2bf(nki); K1h[rq + 64 + j] = h0; K1l[rq + 64 + j] = f2bf(nki - bf2f(h0));
    }
    __syncthreads();                    // done reading sW/sx
    // LDS transpose of V: registers [j, 8 c] -> global VT[i=j][c]
    float* T0 = smem;                   // [64][33]
    #pragma unroll
    for (int cc = 0; cc < 8; ++cc)
        T0[j * 33 + cg * 8 + cc] = av[cc];
    __syncthreads();
    int cc2 = tid & 31, jg = tid >> 5;  // 8 j-rows per thread, coalesced c stores
    #pragma unroll
    for (int jj = 0; jj < 8; ++jj) {
        int jr = jg * 8 + jj;
        float v = T0[jr * 33 + cc2];
        us hh = f2bf(v);
        size_t o = ((size_t)bh * 64 + jr) * C_ + c0 + cc2;
        VTh[o] = hh;
        VTl[o] = f2bf(v - bf2f(hh));
    }
}

// ---------------- MFMA Retention (split-K partials) ----------------
// 768 blocks = 48 parts/bh x 16 bh, ALL co-resident at 3 blocks/CU (52KB LDS).
// Parts: qt<=15 whole (kt 0..qt); qt>=16 split into part0 (kt 0..15) and
// part1 (kt 16..qt). Dispatch ordered size-descending for CU balance.
// Each block writes a 64x64 fp32 partial O tile (re+im) to Pbuf; the reduce
// kernel sums parts and applies the L2 norm.
__global__ __launch_bounds__(256) void retention_kernel(
    const us* __restrict__ Qch, const us* __restrict__ Qcl,
    const us* __restrict__ K1h, const us* __restrict__ K1l,
    const us* __restrict__ VTh, const us* __restrict__ VTl,
    float* __restrict__ Pbuf,
    const float* __restrict__ gamma, const float* __restrict__ qk_scale)
{
    constexpr int SP = 68;             // padded row stride (shorts)
    constexpr int PL = 64 * SP;        // plane size
    __shared__ us smem[6 * PL];        // 52,224 B -> 3 blocks/CU
    us* sSrh = smem;
    us* sSrl = smem + PL;
    us* sSih = smem + 2 * PL;
    us* sSil = smem + 3 * PL;
    us* sVh  = smem + 4 * PL;
    us* sVl  = smem + 5 * PL;

    const int tid = threadIdx.x;
    const int w = tid >> 6, lane = tid & 63;
    const int ln = lane & 15, quad = lane >> 4;
    // ---- work-item mapping (size-descending dispatch) ----
    const int r = (int)blockIdx.x >> 4, bh = (int)blockIdx.x & 15;
    const int h = bh & 7;
    int qt, klo, slot;
    if (r == 0)       { qt = 15; klo = 0;  slot = 15; }
    else if (r == 1)  { qt = 31; klo = 16; slot = 47; }
    else if (r <= 17) { qt = 14 + r; klo = 0; slot = 16 + 2 * (qt - 16); }
    else {
        int u = r - 18, s = 15 - (u >> 1);
        if ((u & 1) == 0) { qt = s - 1;  klo = 0;  slot = qt; }
        else              { qt = 15 + s; klo = 16; slot = 17 + 2 * (qt - 16); }
    }
    const int khi = (qt >= 16 && klo == 0) ? 15 : qt;
    const int qc0 = qt * 64;
    const float lg = log2f(gamma[h]);
    const float inv_scale = 1.0f / qk_scale[0];
    // factorized decay: gamma^(q-k) = gamma^(qc0-kc0) * gamma^qL * gamma^-kL
    float rowf[4], colf[4];
    #pragma unroll
    for (int rr2 = 0; rr2 < 4; ++rr2)
        rowf[rr2] = exp2f(lg * (float)(w * 16 + quad * 4 + rr2));
    #pragma unroll
    for (int nt = 0; nt < 4; ++nt)
        colf[nt] = exp2f(-lg * (float)(nt * 16 + ln));

    // persistent Q A-frags: A[m][k], m = qc0+16w+ln, k = ck*32 + quad*8 + j
    short8 Qh[4], Ql[4];
    {
        size_t qrow = ((size_t)bh * C_ + qc0 + w * 16 + ln) * 128;
        #pragma unroll
        for (int ck = 0; ck < 4; ++ck) {
            size_t off = qrow + ck * 32 + quad * 8;
            Qh[ck] = *(const short8*)(Qch + off);
            Ql[ck] = *(const short8*)(Qcl + off);
        }
    }
    f32x4 zz = {0.0f, 0.0f, 0.0f, 0.0f};
    f32x4 Or[4], Oi[4];
    #pragma unroll
    for (int it = 0; it < 4; ++it) { Or[it] = zz; Oi[it] = zz; }

    const size_t vtb = (size_t)bh * 64 * C_;
    for (int kt = klo; kt <= khi; ++kt) {
        const int kc0 = kt * 64;
        __syncthreads();   // prev phase-B reads of sV done
        // stage V^T tile: sV[i][c-local], 16 shorts/thread/plane
        {
            int i = tid >> 2, seg = (tid & 3) * 16;
            size_t g = vtb + (size_t)i * C_ + kc0 + seg;
            short8 a = *(const short8*)(VTh + g);
            short8 bq = *(const short8*)(VTh + g + 8);
            *(short4v*)&sVh[i * SP + seg]      = __builtin_shufflevector(a, a, 0, 1, 2, 3);
            *(short4v*)&sVh[i * SP + seg + 4]  = __builtin_shufflevector(a, a, 4, 5, 6, 7);
            *(short4v*)&sVh[i * SP + seg + 8]  = __builtin_shufflevector(bq, bq, 0, 1, 2, 3);
            *(short4v*)&sVh[i * SP + seg + 12] = __builtin_shufflevector(bq, bq, 4, 5, 6, 7);
            a  = *(const short8*)(VTl + g);
            bq = *(const short8*)(VTl + g + 8);
            *(short4v*)&sVl[i * SP + seg]      = __builtin_shufflevector(a, a, 0, 1, 2, 3);
            *(short4v*)&sVl[i * SP + seg + 4]  = __builtin_shufflevector(a, a, 4, 5, 6, 7);
            *(short4v*)&sVl[i * SP + seg + 8]  = __builtin_shufflevector(bq, bq, 0, 1, 2, 3);
            *(short4v*)&sVl[i * SP + seg + 12] = __builtin_shufflevector(bq, bq, 4, 5, 6, 7);
        }
        const float tf = exp2f(lg * (float)(qc0 - kc0)) * inv_scale;
        float tr[4];
        #pragma unroll
        for (int rr2 = 0; rr2 < 4; ++rr2) tr[rr2] = tf * rowf[rr2];
        const bool diag = (kt == qt);
        // phase A: 16x16 S-tile pairs, keys kc0+16nt..+15 (B-frags from global)
        #pragma unroll
        for (int nt = 0; nt < 4; ++nt) {
            short8 Kh[4], Kl[4];
            size_t krow = ((size_t)bh * C_ + kc0 + nt * 16 + ln) * 128;
            #pragma unroll
            for (int ck = 0; ck < 4; ++ck) {
                size_t off = krow + ck * 32 + quad * 8;
                Kh[ck] = *(const short8*)(K1h + off);
                Kl[ck] = *(const short8*)(K1l + off);
            }
            f32x4 sr = zz, si = zz;
            #pragma unroll
            for (int ck = 0; ck < 4; ++ck) {
                sr = mfma16(Qh[ck], Kh[ck], sr);
                sr = mfma16(Qh[ck], Kl[ck], sr);
                sr = mfma16(Ql[ck], Kh[ck], sr);
            }
            short8 nKh2 = negbf(Kh[2]), nKh3 = negbf(Kh[3]);
            short8 nKl2 = negbf(Kl[2]), nKl3 = negbf(Kl[3]);
            si = mfma16(Qh[0], nKh2, si); si = mfma16(Qh[0], nKl2, si); si = mfma16(Ql[0], nKh2, si);
            si = mfma16(Qh[1], nKh3, si); si = mfma16(Qh[1], nKl3, si); si = mfma16(Ql[1], nKh3, si);
            si = mfma16(Qh[2], Kh[0], si); si = mfma16(Qh[2], Kl[0], si); si = mfma16(Ql[2], Kh[0], si);
            si = mfma16(Qh[3], Kh[1], si); si = mfma16(Qh[3], Kl[1], si); si = mfma16(Ql[3], Kh[1], si);
            // decay (factorized) + causal mask (diag tile only); truncating split
            const int kL = nt * 16 + ln;
            #pragma unroll
            for (int rr2 = 0; rr2 < 4; ++rr2) {
                float wv = tr[rr2] * colf[nt];
                if (diag && (w * 16 + quad * 4 + rr2 < kL)) wv = 0.0f;
                float a = sr[rr2] * wv, c = si[rr2] * wv;
                int ad = (w * 16 + quad * 4 + rr2) * SP + nt * 16 + ln;
                us h0 = f2bf_t(a); sSrh[ad] = h0; sSrl[ad] = f2bf_t(a - bf2f(h0));
                us h1 = f2bf_t(c); sSih[ad] = h1; sSil[ad] = f2bf_t(c - bf2f(h1));
            }
        }
        __syncthreads();   // sV staging + (wave-private) S writes complete
        // phase B: O[q][i] += S[q][kc] * V[kc][i]
        short8 SrH[2], SrL[2], SiH[2], SiL[2];
        int sb = (w * 16 + ln) * SP;
        #pragma unroll
        for (int ck2 = 0; ck2 < 2; ++ck2) {
            int off = sb + ck2 * 32 + quad * 8;
            SrH[ck2] = lds_frag(&sSrh[off]);
            SrL[ck2] = lds_frag(&sSrl[off]);
            SiH[ck2] = lds_frag(&sSih[off]);
            SiL[ck2] = lds_frag(&sSil[off]);
        }
        #pragma unroll
        for (int it = 0; it < 4; ++it) {
            int vb = (it * 16 + ln) * SP;
            #pragma unroll
            for (int ck2 = 0; ck2 < 2; ++ck2) {
                short8 Vh = lds_frag(&sVh[vb + ck2 * 32 + quad * 8]);
                short8 Vl = lds_frag(&sVl[vb + ck2 * 32 + quad * 8]);
                Or[it] = mfma16(SrH[ck2], Vh, Or[it]);
                Or[it] = mfma16(SrH[ck2], Vl, Or[it]);
                Or[it] = mfma16(SrL[ck2], Vh, Or[it]);
                Oi[it] = mfma16(SiH[ck2], Vh, Oi[it]);
                Oi[it] = mfma16(SiH[ck2], Vl, Oi[it]);
                Oi[it] = mfma16(SiL[ck2], Vh, Oi[it]);
            }
        }
    }
    // write fp32 partial tile: [bh*48+slot][q_local 64][i 64], re then im plane
    float* Pr = Pbuf + ((size_t)(bh * 48 + slot)) * 8192;
    float* Pi = Pr + 4096;
    #pragma unroll
    for (int it = 0; it < 4; ++it) {
        #pragma unroll
        for (int rr2 = 0; rr2 < 4; ++rr2) {
            int qL = w * 16 + quad * 4 + rr2, iX = it * 16 + ln;
            Pr[qL * 64 + iX] = Or[it][rr2];
            Pi[qL * 64 + iX] = Oi[it][rr2];
        }
    }
}

// ---------------- Partial reduce + per-row L2 normalize ----------------
// grid (32 qt, 16 bh), block 256. Thread t: q = t>>2, i = (t&3)*16 .. +15.
__global__ __launch_bounds__(256) void reduce_kernel(
    const float* __restrict__ Pbuf,
    float* __restrict__ OHr, float* __restrict__ OHi)
{
    const int qt = blockIdx.x, bh = blockIdx.y;
    const int h = bh & 7, b = bh >> 3;
    const int t = threadIdx.x;
    const int q = t >> 2, i0 = (t & 3) * 16;
    const int slot0 = (qt < 16) ? qt : 16 + 2 * (qt - 16);
    const int nparts = (qt < 16) ? 1 : 2;
    const float* P0 = Pbuf + ((size_t)(bh * 48 + slot0)) * 8192 + q * 64 + i0;
    float orv[16], oiv[16];
    #pragma unroll
    for (int s4 = 0; s4 < 4; ++s4) {
        *(float4*)&orv[s4 * 4] = *(const float4*)(P0 + s4 * 4);
        *(float4*)&oiv[s4 * 4] = *(const float4*)(P0 + 4096 + s4 * 4);
    }
    if (nparts == 2) {
        const float* P1 = P0 + 8192;
        #pragma unroll
        for (int s4 = 0; s4 < 4; ++s4) {
            float4 a = *(const float4*)(P1 + s4 * 4);
            float4 c = *(const float4*)(P1 + 4096 + s4 * 4);
            orv[s4 * 4]     += a.x; orv[s4 * 4 + 1] += a.y;
            orv[s4 * 4 + 2] += a.z; orv[s4 * 4 + 3] += a.w;
            oiv[s4 * 4]     += c.x; oiv[s4 * 4 + 1] += c.y;
            oiv[s4 * 4 + 2] += c.z; oiv[s4 * 4 + 3] += c.w;
        }
    }
    float ss = 0.0f;
    #pragma unroll
    for (int k = 0; k < 16; ++k) ss += orv[k] * orv[k] + oiv[k] * oiv[k];
    ss += __shfl_xor(ss, 1);
    ss += __shfl_xor(ss, 2);
    float rn = rsqrtf(ss);
    size_t o = (((size_t)(b * C_ + qt * 64 + q)) * H_ + h) * HW_ + i0;
    float tmp[16];
    #pragma unroll
    for (int k = 0; k < 16; ++k) tmp[k] = orv[k] * rn;
    #pragma unroll
    for (int s4 = 0; s4 < 4; ++s4) *(float4*)&OHr[o + s4 * 4] = *(float4*)&tmp[s4 * 4];
    #pragma unroll
    for (int k = 0; k < 16; ++k) tmp[k] = oiv[k] * rn;
    #pragma unroll
    for (int s4 = 0; s4 < 4; ++s4) *(float4*)&OHi[o + s4 * 4] = *(float4*)&tmp[s4 * 4];
}

// ---------------- fp32 GEMM: C[M,N] = A[M,K]*B[K,N] ----------------
// BM=BN=128, BK=8, 256 threads, 8x8 micro-tile.
// mode 0: plain store; mode 1: complex interleave (rows [0,M/2) = re, rest = im);
// mode 2: store real plane only.
// NOTE: epilogue loops MUST be fully unrolled — dynamic acc[im][in] indexing
// in a non-unrolled loop demotes the whole accumulator to scratch (R1: 52
// VGPRs, 2.2 GB scratch writes, 1950 us).
__global__ __launch_bounds__(256) void gemm_kernel(
    const float* __restrict__ A, const float* __restrict__ Bm,
    float* __restrict__ Cout, int M, int N, int K, int mode)
{
    __shared__ float sA[8][132];
    __shared__ float sB[8][132];
    int tid = threadIdx.x;
    int bm = blockIdx.x * 128, bn = blockIdx.y * 128;
    int tx = tid & 15, ty = tid >> 4;
    int m0 = ty * 8, n0 = tx * 8;
    float acc[8][8] = {};
    for (int k0 = 0; k0 < K; k0 += 8) {
        #pragma unroll
        for (int t = tid; t < 1024; t += 256) {
            int kk = t & 7, m = t >> 3;
            sA[kk][m] = A[(size_t)(bm + m) * K + k0 + kk];
        }
        #pragma unroll
        for (int t = tid; t < 1024; t += 256) {
            int n = t & 127, kk = t >> 7;
            sB[kk][n] = Bm[(size_t)(k0 + kk) * N + bn + n];
        }
        __syncthreads();
        #pragma unroll
        for (int kk = 0; kk < 8; ++kk) {
            float a_[8], b_[8];
            *(float4*)&a_[0] = *(const float4*)&sA[kk][m0];
            *(float4*)&a_[4] = *(const float4*)&sA[kk][m0 + 4];
            *(float4*)&b_[0] = *(const float4*)&sB[kk][n0];
            *(float4*)&b_[4] = *(const float4*)&sB[kk][n0 + 4];
            #pragma unroll
            for (int im = 0; im < 8; ++im)
                #pragma unroll
                for (int in = 0; in < 8; ++in)
                    acc[im][in] += a_[im] * b_[in];
        }
        __syncthreads();
    }
    int half = M >> 1;
    #pragma unroll
    for (int im = 0; im < 8; ++im) {
        int m = bm + m0 + im;
        #pragma unroll
        for (int in = 0; in < 8; ++in) {
            int n = bn + n0 + in;
            float vv = acc[im][in];
            if (mode == 0) {
                Cout[(size_t)m * N + n] = vv;
            } else if (mode == 1) {
                if (m < half) Cout[2 * ((size_t)m * N + n)] = vv;
                else          Cout[2 * ((size_t)(m - half) * N + n) + 1] = vv;
            } else {
                if (m < half) Cout[(size_t)m * N + n] = vv;
            }
        }
    }
}

// ---------------- complex gate: oh' = oh*g / (1 + exp(-2g)), g complex ----------------
__global__ __launch_bounds__(256) void gate_kernel(
    const float* __restrict__ OHr, const float* __restrict__ OHi,
    const float* __restrict__ G,
    float* __restrict__ O2r, float* __restrict__ O2i, int n)
{
    int idx = blockIdx.x * 256 + threadIdx.x;
    if (idx >= n) return;
    float gr = G[idx], gi = G[idx + n];
    float hr = OHr[idx], hi = OHi[idx];
    float e = expf(-2.0f * gr);
    float sn, cs;
    sincosf(2.0f * gi, &sn, &cs);
    float dr = 1.0f + e * cs;
    float di = -e * sn;
    float nr = hr * gr - hi * gi;
    float ni = hr * gi + hi * gr;
    float inv = 1.0f / (dr * dr + di * di);
    O2r[idx] = (nr * dr + ni * di) * inv;
    O2i[idx] = (ni * dr - nr * di) * inv;
}

extern "C" void kernel_launch(void* const* d_in, const int* in_sizes, int n_in,
                              void* d_out, int out_size, void* d_ws, size_t ws_size,
                              hipStream_t stream)
{
    const float* x     = (const float*)d_in[0];
    const float* WQ    = (const float*)d_in[1];
    const float* WK    = (const float*)d_in[2];
    const float* WV    = (const float*)d_in[3];
    const float* theta = (const float*)d_in[4];
    const float* gamma = (const float*)d_in[5];
    // d_in[6] target_norm: dead in reference
    const float* qk    = (const float*)d_in[7];
    const float* WO    = (const float*)d_in[8];
    const float* WG    = (const float*)d_in[9];
    float* out = (float*)d_out;

    const size_t N1 = (size_t)B_ * H_ * C_ * HW_;       // 2,097,152
    const size_t SQ = (size_t)B_ * H_ * C_ * 128;       // shorts per Qcat/K1 plane
    const size_t SV = (size_t)B_ * H_ * HW_ * C_;       // shorts per VT plane
    us* usw = (us*)d_ws;
    us *Qch = usw,            *Qcl = usw + SQ,
       *K1h = usw + 2 * SQ,   *K1l = usw + 3 * SQ,
       *VTh = usw + 4 * SQ,   *VTl = usw + 4 * SQ + SV; // shorts end at 5*N1 floats
    float* fw = (float*)d_ws;
    float *OHr = fw + 5 * N1, *OHi = fw + 6 * N1;
    float *G   = fw + 7 * N1;                           // 2*N1 (re, im planes)
    float *O2r = fw + 9 * N1, *O2i = fw + 10 * N1;
    // Pbuf (3*N1 floats = 768 x 8192) overlays G/O2r: partials are dead before
    // the G-GEMM writes, which runs after reduce_kernel.
    float *Pbuf = fw + 7 * N1;

    proj_kernel<<<dim3(C_ / 32, B_ * H_), 256, 0, stream>>>(
        x, WQ, WK, WV, theta, Qch, Qcl, K1h, K1l, VTh, VTl);
    retention_kernel<<<dim3(768), 256, 0, stream>>>(
        Qch, Qcl, K1h, K1l, VTh, VTl, Pbuf, gamma, qk);
    reduce_kernel<<<dim3(32, B_ * H_), 256, 0, stream>>>(Pbuf, OHr, OHi);

    const int M = 2 * B_ * C_;  // 8192 rows: [re; im] planes
    gemm_kernel<<<dim3(M / 128, HD_ / 128), 256, 0, stream>>>(
        OHr, WG, G, M, HD_, HD_, 0);

    int n1i = (int)N1;
    gate_kernel<<<dim3((n1i + 255) / 256), 256, 0, stream>>>(
        OHr, OHi, G, O2r, O2i, n1i);

    int outmode = (out_size >= (int)(2 * N1)) ? 1 : 2;
    gemm_kernel<<<dim3(M / 128, HD_ / 128), 256, 0, stream>>>(
        O2r, WO, out, M, HD_, HD_, outmode);
}

// Round 7
// 365.063 us; speedup vs baseline: 4.5365x; 1.5593x over previous
//
#include <hip/hip_runtime.h>
#include <cstdint>
#include <cstddef>

#define B_  2
#define H_  8
#define C_  2048
#define HW_ 64
#define HD_ 512   // H_*HW_

typedef __attribute__((ext_vector_type(8))) short short8;
typedef __attribute__((ext_vector_type(4))) short short4v;
typedef __attribute__((ext_vector_type(4))) float f32x4;
typedef __attribute__((ext_vector_type(4))) int   int4v;
typedef unsigned short us;

static __device__ inline us f2bf(float f) {           // RNE
    unsigned u = __builtin_bit_cast(unsigned, f);
    u = u + 0x7FFFu + ((u >> 16) & 1u);
    return (us)(u >> 16);
}
static __device__ inline us f2bf_t(float f) {         // truncate (hot path)
    return (us)(__builtin_bit_cast(unsigned, f) >> 16);
}
static __device__ inline float bf2f(us s) {
    unsigned u = ((unsigned)s) << 16;
    return __builtin_bit_cast(float, u);
}
static __device__ inline f32x4 mfma16(short8 a, short8 b, f32x4 c) {
    return __builtin_amdgcn_mfma_f32_16x16x32_bf16(a, b, c, 0, 0, 0);
}
static __device__ inline short8 negbf(short8 v) {
    int4v u = __builtin_bit_cast(int4v, v);
    u ^= (int)0x80008000;
    return __builtin_bit_cast(short8, u);
}
// b64-pair LDS fragment load (rows padded to 68 shorts -> only 8B-aligned)
static __device__ inline short8 lds_frag(const us* p) {
    short4v a = *(const short4v*)p;
    short4v b = *(const short4v*)(p + 4);
    return __builtin_shufflevector(a, b, 0, 1, 2, 3, 4, 5, 6, 7);
}

// ---------------- Projection + rotary phase ----------------
__global__ __launch_bounds__(256) void proj_kernel(
    const float* __restrict__ x, const float* __restrict__ WQ,
    const float* __restrict__ WK, const float* __restrict__ WV,
    const float* __restrict__ theta,
    us* __restrict__ Qch, us* __restrict__ Qcl,
    us* __restrict__ K1h, us* __restrict__ K1l,
    us* __restrict__ VTh, us* __restrict__ VTl)
{
    __shared__ float smem[3 * 64 * 65 + 32 * 65];
    float* sW = smem;               // [3][64][65]
    float* sx = smem + 3 * 64 * 65; // [32][65]
    int tid = threadIdx.x;
    int bh = blockIdx.y; int h = bh & 7;
    int c0 = blockIdx.x * 32;
    for (int t = tid; t < 64 * 64; t += 256) {
        int j = t & 63, i = t >> 6;
        int g = (h * 64 + i) * 64 + j;
        sW[0 * 64 * 65 + i * 65 + j] = WQ[g];
        sW[1 * 64 * 65 + i * 65 + j] = WK[g];
        sW[2 * 64 * 65 + i * 65 + j] = WV[g];
    }
    for (int t = tid; t < 32 * 64; t += 256) {
        int i = t & 63, c = t >> 6;
        sx[c * 65 + i] = x[((size_t)((bh >> 3) * C_ + c0 + c)) * HD_ + h * 64 + i];
    }
    __syncthreads();
    int j = tid & 63, cg = tid >> 6;
    float aq[8] = {}, ak[8] = {}, av[8] = {};
    for (int i = 0; i < 64; ++i) {
        float w0 = sW[0 * 64 * 65 + i * 65 + j];
        float w1 = sW[1 * 64 * 65 + i * 65 + j];
        float w2 = sW[2 * 64 * 65 + i * 65 + j];
        #pragma unroll
        for (int cc = 0; cc < 8; ++cc) {
            float xv = sx[(cg * 8 + cc) * 65 + i];
            aq[cc] += xv * w0;
            ak[cc] += xv * w1;
            av[cc] += xv * w2;
        }
    }
    float th = theta[h * 64 + j];
    #pragma unroll
    for (int cc = 0; cc < 8; ++cc) {
        int c = c0 + cg * 8 + cc;
        float sn, cs;
        sincosf((float)c * th, &sn, &cs);
        float qr = aq[cc] * cs, qi = aq[cc] * sn;
        float kr = ak[cc] * cs, nki = ak[cc] * sn;   // nki = -Ki
        size_t rq = ((size_t)bh * C_ + c) * 128;
        us h0;
        h0 = f2bf(qr);  Qch[rq + j]      = h0; Qcl[rq + j]      = f2bf(qr  - bf2f(h0));
        h0 = f2bf(qi);  Qch[rq + 64 + j] = h0; Qcl[rq + 64 + j] = f2bf(qi  - bf2f(h0));
        h0 = f2bf(kr);  K1h[rq + j]      = h0; K1l[rq + j]      = f2bf(kr  - bf2f(h0));
        h0 = f2bf(nki); K1h[rq + 64 + j] = h0; K1l[rq + 64 + j] = f2bf(nki - bf2f(h0));
    }
    __syncthreads();
    float* T0 = smem;                   // [64][33]
    #pragma unroll
    for (int cc = 0; cc < 8; ++cc)
        T0[j * 33 + cg * 8 + cc] = av[cc];
    __syncthreads();
    int cc2 = tid & 31, jg = tid >> 5;
    #pragma unroll
    for (int jj = 0; jj < 8; ++jj) {
        int jr = jg * 8 + jj;
        float v = T0[jr * 33 + cc2];
        us hh = f2bf(v);
        size_t o = ((size_t)bh * 64 + jr) * C_ + c0 + cc2;
        VTh[o] = hh;
        VTl[o] = f2bf(v - bf2f(hh));
    }
}

// ---------------- MFMA Retention (split-K partials) ----------------
__global__ __launch_bounds__(256) void retention_kernel(
    const us* __restrict__ Qch, const us* __restrict__ Qcl,
    const us* __restrict__ K1h, const us* __restrict__ K1l,
    const us* __restrict__ VTh, const us* __restrict__ VTl,
    float* __restrict__ Pbuf,
    const float* __restrict__ gamma, const float* __restrict__ qk_scale)
{
    constexpr int SP = 68;
    constexpr int PL = 64 * SP;
    __shared__ us smem[6 * PL];        // 52,224 B -> 3 blocks/CU
    us* sSrh = smem;
    us* sSrl = smem + PL;
    us* sSih = smem + 2 * PL;
    us* sSil = smem + 3 * PL;
    us* sVh  = smem + 4 * PL;
    us* sVl  = smem + 5 * PL;

    const int tid = threadIdx.x;
    const int w = tid >> 6, lane = tid & 63;
    const int ln = lane & 15, quad = lane >> 4;
    const int r = (int)blockIdx.x >> 4, bh = (int)blockIdx.x & 15;
    const int h = bh & 7;
    int qt, klo, slot;
    if (r == 0)       { qt = 15; klo = 0;  slot = 15; }
    else if (r == 1)  { qt = 31; klo = 16; slot = 47; }
    else if (r <= 17) { qt = 14 + r; klo = 0; slot = 16 + 2 * (qt - 16); }
    else {
        int u = r - 18, s = 15 - (u >> 1);
        if ((u & 1) == 0) { qt = s - 1;  klo = 0;  slot = qt; }
        else              { qt = 15 + s; klo = 16; slot = 17 + 2 * (qt - 16); }
    }
    const int khi = (qt >= 16 && klo == 0) ? 15 : qt;
    const int qc0 = qt * 64;
    const float lg = log2f(gamma[h]);
    const float inv_scale = 1.0f / qk_scale[0];
    float rowf[4], colf[4];
    #pragma unroll
    for (int rr2 = 0; rr2 < 4; ++rr2)
        rowf[rr2] = exp2f(lg * (float)(w * 16 + quad * 4 + rr2));
    #pragma unroll
    for (int nt = 0; nt < 4; ++nt)
        colf[nt] = exp2f(-lg * (float)(nt * 16 + ln));

    short8 Qh[4], Ql[4];
    {
        size_t qrow = ((size_t)bh * C_ + qc0 + w * 16 + ln) * 128;
        #pragma unroll
        for (int ck = 0; ck < 4; ++ck) {
            size_t off = qrow + ck * 32 + quad * 8;
            Qh[ck] = *(const short8*)(Qch + off);
            Ql[ck] = *(const short8*)(Qcl + off);
        }
    }
    f32x4 zz = {0.0f, 0.0f, 0.0f, 0.0f};
    f32x4 Or[4], Oi[4];
    #pragma unroll
    for (int it = 0; it < 4; ++it) { Or[it] = zz; Oi[it] = zz; }

    const size_t vtb = (size_t)bh * 64 * C_;
    for (int kt = klo; kt <= khi; ++kt) {
        const int kc0 = kt * 64;
        __syncthreads();
        {
            int i = tid >> 2, seg = (tid & 3) * 16;
            size_t g = vtb + (size_t)i * C_ + kc0 + seg;
            short8 a = *(const short8*)(VTh + g);
            short8 bq = *(const short8*)(VTh + g + 8);
            *(short4v*)&sVh[i * SP + seg]      = __builtin_shufflevector(a, a, 0, 1, 2, 3);
            *(short4v*)&sVh[i * SP + seg + 4]  = __builtin_shufflevector(a, a, 4, 5, 6, 7);
            *(short4v*)&sVh[i * SP + seg + 8]  = __builtin_shufflevector(bq, bq, 0, 1, 2, 3);
            *(short4v*)&sVh[i * SP + seg + 12] = __builtin_shufflevector(bq, bq, 4, 5, 6, 7);
            a  = *(const short8*)(VTl + g);
            bq = *(const short8*)(VTl + g + 8);
            *(short4v*)&sVl[i * SP + seg]      = __builtin_shufflevector(a, a, 0, 1, 2, 3);
            *(short4v*)&sVl[i * SP + seg + 4]  = __builtin_shufflevector(a, a, 4, 5, 6, 7);
            *(short4v*)&sVl[i * SP + seg + 8]  = __builtin_shufflevector(bq, bq, 0, 1, 2, 3);
            *(short4v*)&sVl[i * SP + seg + 12] = __builtin_shufflevector(bq, bq, 4, 5, 6, 7);
        }
        const float tf = exp2f(lg * (float)(qc0 - kc0)) * inv_scale;
        float tr[4];
        #pragma unroll
        for (int rr2 = 0; rr2 < 4; ++rr2) tr[rr2] = tf * rowf[rr2];
        const bool diag = (kt == qt);
        #pragma unroll
        for (int nt = 0; nt < 4; ++nt) {
            short8 Kh[4], Kl[4];
            size_t krow = ((size_t)bh * C_ + kc0 + nt * 16 + ln) * 128;
            #pragma unroll
            for (int ck = 0; ck < 4; ++ck) {
                size_t off = krow + ck * 32 + quad * 8;
                Kh[ck] = *(const short8*)(K1h + off);
                Kl[ck] = *(const short8*)(K1l + off);
            }
            f32x4 sr = zz, si = zz;
            #pragma unroll
            for (int ck = 0; ck < 4; ++ck) {
                sr = mfma16(Qh[ck], Kh[ck], sr);
                sr = mfma16(Qh[ck], Kl[ck], sr);
                sr = mfma16(Ql[ck], Kh[ck], sr);
            }
            short8 nKh2 = negbf(Kh[2]), nKh3 = negbf(Kh[3]);
            short8 nKl2 = negbf(Kl[2]), nKl3 = negbf(Kl[3]);
            si = mfma16(Qh[0], nKh2, si); si = mfma16(Qh[0], nKl2, si); si = mfma16(Ql[0], nKh2, si);
            si = mfma16(Qh[1], nKh3, si); si = mfma16(Qh[1], nKl3, si); si = mfma16(Ql[1], nKh3, si);
            si = mfma16(Qh[2], Kh[0], si); si = mfma16(Qh[2], Kl[0], si); si = mfma16(Ql[2], Kh[0], si);
            si = mfma16(Qh[3], Kh[1], si); si = mfma16(Qh[3], Kl[1], si); si = mfma16(Ql[3], Kh[1], si);
            const int kL = nt * 16 + ln;
            #pragma unroll
            for (int rr2 = 0; rr2 < 4; ++rr2) {
                float wv = tr[rr2] * colf[nt];
                if (diag && (w * 16 + quad * 4 + rr2 < kL)) wv = 0.0f;
                float a = sr[rr2] * wv, c = si[rr2] * wv;
                int ad = (w * 16 + quad * 4 + rr2) * SP + nt * 16 + ln;
                us h0 = f2bf_t(a); sSrh[ad] = h0; sSrl[ad] = f2bf_t(a - bf2f(h0));
                us h1 = f2bf_t(c); sSih[ad] = h1; sSil[ad] = f2bf_t(c - bf2f(h1));
            }
        }
        __syncthreads();
        short8 SrH[2], SrL[2], SiH[2], SiL[2];
        int sb = (w * 16 + ln) * SP;
        #pragma unroll
        for (int ck2 = 0; ck2 < 2; ++ck2) {
            int off = sb + ck2 * 32 + quad * 8;
            SrH[ck2] = lds_frag(&sSrh[off]);
            SrL[ck2] = lds_frag(&sSrl[off]);
            SiH[ck2] = lds_frag(&sSih[off]);
            SiL[ck2] = lds_frag(&sSil[off]);
        }
        #pragma unroll
        for (int it = 0; it < 4; ++it) {
            int vb = (it * 16 + ln) * SP;
            #pragma unroll
            for (int ck2 = 0; ck2 < 2; ++ck2) {
                short8 Vh = lds_frag(&sVh[vb + ck2 * 32 + quad * 8]);
                short8 Vl = lds_frag(&sVl[vb + ck2 * 32 + quad * 8]);
                Or[it] = mfma16(SrH[ck2], Vh, Or[it]);
                Or[it] = mfma16(SrH[ck2], Vl, Or[it]);
                Or[it] = mfma16(SrL[ck2], Vh, Or[it]);
                Oi[it] = mfma16(SiH[ck2], Vh, Oi[it]);
                Oi[it] = mfma16(SiH[ck2], Vl, Oi[it]);
                Oi[it] = mfma16(SiL[ck2], Vh, Oi[it]);
            }
        }
    }
    float* Pr = Pbuf + ((size_t)(bh * 48 + slot)) * 8192;
    float* Pi = Pr + 4096;
    #pragma unroll
    for (int it = 0; it < 4; ++it) {
        #pragma unroll
        for (int rr2 = 0; rr2 < 4; ++rr2) {
            int qL = w * 16 + quad * 4 + rr2, iX = it * 16 + ln;
            Pr[qL * 64 + iX] = Or[it][rr2];
            Pi[qL * 64 + iX] = Oi[it][rr2];
        }
    }
}

// ---------------- Partial reduce + L2 norm -> bf16 h/l activation planes ----
// A1 layout: [8192 rows][512 cols]; rows 0..4095 = re (b*C+c), 4096.. = im.
__global__ __launch_bounds__(256) void reduce_kernel(
    const float* __restrict__ Pbuf,
    us* __restrict__ A1h, us* __restrict__ A1l)
{
    const int qt = blockIdx.x, bh = blockIdx.y;
    const int h = bh & 7, b = bh >> 3;
    const int t = threadIdx.x;
    const int q = t >> 2, i0 = (t & 3) * 16;
    const int slot0 = (qt < 16) ? qt : 16 + 2 * (qt - 16);
    const int nparts = (qt < 16) ? 1 : 2;
    const float* P0 = Pbuf + ((size_t)(bh * 48 + slot0)) * 8192 + q * 64 + i0;
    float orv[16], oiv[16];
    #pragma unroll
    for (int s4 = 0; s4 < 4; ++s4) {
        *(float4*)&orv[s4 * 4] = *(const float4*)(P0 + s4 * 4);
        *(float4*)&oiv[s4 * 4] = *(const float4*)(P0 + 4096 + s4 * 4);
    }
    if (nparts == 2) {
        const float* P1 = P0 + 8192;
        #pragma unroll
        for (int s4 = 0; s4 < 4; ++s4) {
            float4 a = *(const float4*)(P1 + s4 * 4);
            float4 c = *(const float4*)(P1 + 4096 + s4 * 4);
            orv[s4 * 4]     += a.x; orv[s4 * 4 + 1] += a.y;
            orv[s4 * 4 + 2] += a.z; orv[s4 * 4 + 3] += a.w;
            oiv[s4 * 4]     += c.x; oiv[s4 * 4 + 1] += c.y;
            oiv[s4 * 4 + 2] += c.z; oiv[s4 * 4 + 3] += c.w;
        }
    }
    float ss = 0.0f;
    #pragma unroll
    for (int k = 0; k < 16; ++k) ss += orv[k] * orv[k] + oiv[k] * oiv[k];
    ss += __shfl_xor(ss, 1);
    ss += __shfl_xor(ss, 2);
    float rn = rsqrtf(ss);
    const size_t N1 = (size_t)B_ * H_ * C_ * HW_;
    size_t o = (((size_t)(b * C_ + qt * 64 + q)) * H_ + h) * HW_ + i0;
    us th[16], tl[16];
    #pragma unroll
    for (int k = 0; k < 16; ++k) {
        float v = orv[k] * rn;
        us hh = f2bf(v); th[k] = hh; tl[k] = f2bf(v - bf2f(hh));
    }
    *(short8*)&A1h[o] = *(short8*)&th[0]; *(short8*)&A1h[o + 8] = *(short8*)&th[8];
    *(short8*)&A1l[o] = *(short8*)&tl[0]; *(short8*)&A1l[o + 8] = *(short8*)&tl[8];
    #pragma unroll
    for (int k = 0; k < 16; ++k) {
        float v = oiv[k] * rn;
        us hh = f2bf(v); th[k] = hh; tl[k] = f2bf(v - bf2f(hh));
    }
    *(short8*)&A1h[N1 + o] = *(short8*)&th[0]; *(short8*)&A1h[N1 + o + 8] = *(short8*)&th[8];
    *(short8*)&A1l[N1 + o] = *(short8*)&tl[0]; *(short8*)&A1l[N1 + o + 8] = *(short8*)&tl[8];
}

// ---------------- Weight transpose + bf16 split: WT[n][k] = W[k][n] --------
__global__ __launch_bounds__(256) void wcvt_kernel(
    const float* __restrict__ WG, const float* __restrict__ WO,
    us* __restrict__ Gh, us* __restrict__ Gl,
    us* __restrict__ Oh, us* __restrict__ Ol)
{
    __shared__ float T[32 * 33];
    const float* src = blockIdx.z ? WO : WG;
    us* dh = blockIdx.z ? Oh : Gh;
    us* dl = blockIdx.z ? Ol : Gl;
    int k0 = blockIdx.x * 32, n0 = blockIdx.y * 32;
    int c = threadIdx.x & 31, r8 = threadIdx.x >> 5;
    #pragma unroll
    for (int rr = 0; rr < 4; ++rr) {
        int r = r8 * 4 + rr;
        T[r * 33 + c] = src[(size_t)(k0 + r) * 512 + n0 + c];
    }
    __syncthreads();
    #pragma unroll
    for (int rr = 0; rr < 4; ++rr) {
        int r = r8 * 4 + rr;            // n-local
        float v = T[c * 33 + r];        // [k-local = c][n-local = r]
        us hh = f2bf(v);
        size_t o = (size_t)(n0 + r) * 512 + k0 + c;
        dh[o] = hh; dl[o] = f2bf(v - bf2f(hh));
    }
}

// ---------------- split-bf16 MFMA GEMM: C[8192,512] = A * W (WT given) -----
// No LDS, no barriers: A/B frags read directly from global (16B row-chunks),
// B is L1/L2-resident, A deduped in XCD L2. BM=128 BN=64, grid (64,8) = 2/CU.
// mode 0: plain fp32 store; mode 1: complex interleave; mode 2: re plane only.
__global__ __launch_bounds__(256) void gemm_mfma_kernel(
    const us* __restrict__ Ah, const us* __restrict__ Al,
    const us* __restrict__ BTh, const us* __restrict__ BTl,
    float* __restrict__ Cout, int mode)
{
    const int tid = threadIdx.x;
    const int w = tid >> 6, lane = tid & 63;
    const int ln = lane & 15, quad = lane >> 4;
    const int bm = blockIdx.x * 128 + w * 32;
    const int bn = blockIdx.y * 64;
    f32x4 acc[2][4];
    #pragma unroll
    for (int mt = 0; mt < 2; ++mt)
        #pragma unroll
        for (int nt = 0; nt < 4; ++nt) acc[mt][nt] = (f32x4){0.f, 0.f, 0.f, 0.f};
    const us* pA[2][2];
    const us* pB[4][2];
    #pragma unroll
    for (int mt = 0; mt < 2; ++mt) {
        size_t r = (size_t)(bm + mt * 16 + ln) * 512 + quad * 8;
        pA[mt][0] = Ah + r; pA[mt][1] = Al + r;
    }
    #pragma unroll
    for (int nt = 0; nt < 4; ++nt) {
        size_t r = (size_t)(bn + nt * 16 + ln) * 512 + quad * 8;
        pB[nt][0] = BTh + r; pB[nt][1] = BTl + r;
    }
    #pragma unroll
    for (int ks = 0; ks < 16; ++ks) {
        const int ko = ks * 32;
        short8 Af[2][2], Bf[4][2];
        #pragma unroll
        for (int mt = 0; mt < 2; ++mt) {
            Af[mt][0] = *(const short8*)(pA[mt][0] + ko);
            Af[mt][1] = *(const short8*)(pA[mt][1] + ko);
        }
        #pragma unroll
        for (int nt = 0; nt < 4; ++nt) {
            Bf[nt][0] = *(const short8*)(pB[nt][0] + ko);
            Bf[nt][1] = *(const short8*)(pB[nt][1] + ko);
        }
        #pragma unroll
        for (int mt = 0; mt < 2; ++mt)
            #pragma unroll
            for (int nt = 0; nt < 4; ++nt) {
                acc[mt][nt] = mfma16(Af[mt][0], Bf[nt][0], acc[mt][nt]);
                acc[mt][nt] = mfma16(Af[mt][0], Bf[nt][1], acc[mt][nt]);
                acc[mt][nt] = mfma16(Af[mt][1], Bf[nt][0], acc[mt][nt]);
            }
    }
    #pragma unroll
    for (int mt = 0; mt < 2; ++mt)
        #pragma unroll
        for (int nt = 0; nt < 4; ++nt)
            #pragma unroll
            for (int r = 0; r < 4; ++r) {
                int m = bm + mt * 16 + quad * 4 + r;
                int n = bn + nt * 16 + ln;
                float v = acc[mt][nt][r];
                if (mode == 0) {
                    Cout[(size_t)m * 512 + n] = v;
                } else if (mode == 1) {
                    if (m < 4096) Cout[2 * ((size_t)m * 512 + n)] = v;
                    else          Cout[2 * ((size_t)(m - 4096) * 512 + n) + 1] = v;
                } else {
                    if (m < 4096) Cout[(size_t)m * 512 + n] = v;
                }
            }
}

// ---------------- complex gate: oh' = oh*g / (1 + exp(-2g)) ----------------
// Reads bf16 h/l activations + fp32 G; writes bf16 h/l gated activations.
__global__ __launch_bounds__(256) void gate_kernel(
    const us* __restrict__ A1h, const us* __restrict__ A1l,
    const float* __restrict__ G,
    us* __restrict__ A2h, us* __restrict__ A2l, int n)
{
    int idx = (blockIdx.x * 256 + threadIdx.x) * 4;
    if (idx >= n) return;
    float4 grv = *(const float4*)&G[idx];
    float4 giv = *(const float4*)&G[idx + n];
    short4v hrh = *(const short4v*)&A1h[idx];
    short4v hrl = *(const short4v*)&A1l[idx];
    short4v hih = *(const short4v*)&A1h[n + idx];
    short4v hil = *(const short4v*)&A1l[n + idx];
    float grs[4] = {grv.x, grv.y, grv.z, grv.w};
    float gis[4] = {giv.x, giv.y, giv.z, giv.w};
    us rh[4], rl[4], ih_[4], il_[4];
    #pragma unroll
    for (int k = 0; k < 4; ++k) {
        float gr = grs[k], gi = gis[k];
        float hr = bf2f((us)hrh[k]) + bf2f((us)hrl[k]);
        float hi = bf2f((us)hih[k]) + bf2f((us)hil[k]);
        float e = expf(-2.0f * gr);
        float sn, cs;
        sincosf(2.0f * gi, &sn, &cs);
        float dr = 1.0f + e * cs;
        float di = -e * sn;
        float nr = hr * gr - hi * gi;
        float ni = hr * gi + hi * gr;
        float inv = 1.0f / (dr * dr + di * di);
        float o2r = (nr * dr + ni * di) * inv;
        float o2i = (ni * dr - nr * di) * inv;
        us t = f2bf(o2r); rh[k] = t; rl[k] = f2bf(o2r - bf2f(t));
        t = f2bf(o2i); ih_[k] = t; il_[k] = f2bf(o2i - bf2f(t));
    }
    *(short4v*)&A2h[idx]     = *(short4v*)&rh[0];
    *(short4v*)&A2l[idx]     = *(short4v*)&rl[0];
    *(short4v*)&A2h[n + idx] = *(short4v*)&ih_[0];
    *(short4v*)&A2l[n + idx] = *(short4v*)&il_[0];
}

extern "C" void kernel_launch(void* const* d_in, const int* in_sizes, int n_in,
                              void* d_out, int out_size, void* d_ws, size_t ws_size,
                              hipStream_t stream)
{
    const float* x     = (const float*)d_in[0];
    const float* WQ    = (const float*)d_in[1];
    const float* WK    = (const float*)d_in[2];
    const float* WV    = (const float*)d_in[3];
    const float* theta = (const float*)d_in[4];
    const float* gamma = (const float*)d_in[5];
    const float* qk    = (const float*)d_in[7];
    const float* WO    = (const float*)d_in[8];
    const float* WG    = (const float*)d_in[9];
    float* out = (float*)d_out;

    const size_t N1 = (size_t)B_ * H_ * C_ * HW_;       // 2,097,152
    const size_t SQ = (size_t)B_ * H_ * C_ * 128;       // 4,194,304 shorts
    const size_t SV = (size_t)B_ * H_ * HW_ * C_;       // 2,097,152 shorts
    us* usw = (us*)d_ws;
    us *Qch = usw,            *Qcl = usw + SQ,
       *K1h = usw + 2 * SQ,   *K1l = usw + 3 * SQ,
       *VTh = usw + 4 * SQ,   *VTl = usw + 4 * SQ + SV; // shorts end at 5*N1 floats
    // overlays (lifetimes disjoint):
    us *A1h = Qch, *A1l = Qcl;                 // written by reduce (Q dead)
    us *WTGh = K1h,            *WTGl = K1h + 262144,
       *WTOh = K1h + 524288,  *WTOl = K1h + 786432;     // written by wcvt (K1 dead)
    float* fw = (float*)d_ws;
    float *G   = fw + 7 * N1;                           // 2*N1 fp32
    us *A2h = (us*)(fw + 9 * N1), *A2l = (us*)(fw + 10 * N1);
    float *Pbuf = fw + 7 * N1;                          // 3*N1, dead before G/A2

    proj_kernel<<<dim3(C_ / 32, B_ * H_), 256, 0, stream>>>(
        x, WQ, WK, WV, theta, Qch, Qcl, K1h, K1l, VTh, VTl);
    retention_kernel<<<dim3(768), 256, 0, stream>>>(
        Qch, Qcl, K1h, K1l, VTh, VTl, Pbuf, gamma, qk);
    reduce_kernel<<<dim3(32, B_ * H_), 256, 0, stream>>>(Pbuf, A1h, A1l);
    wcvt_kernel<<<dim3(16, 16, 2), 256, 0, stream>>>(
        WG, WO, WTGh, WTGl, WTOh, WTOl);

    gemm_mfma_kernel<<<dim3(64, 8), 256, 0, stream>>>(
        A1h, A1l, WTGh, WTGl, G, 0);

    int n1i = (int)N1;
    gate_kernel<<<dim3(n1i / 1024), 256, 0, stream>>>(
        A1h, A1l, G, A2h, A2l, n1i);

    int outmode = (out_size >= (int)(2 * N1)) ? 1 : 2;
    gemm_mfma_kernel<<<dim3(64, 8), 256, 0, stream>>>(
        A2h, A2l, WTOh, WTOl, out, outmode);
}